// Round 4
// baseline (435.508 us; speedup 1.0000x reference)
//
#include <hip/hip_runtime.h>
#include <math.h>

#define N_NODES  50000
#define N_EDGES  800000
#define IN_F     128
#define HID_F    64
#define OUT_F    32
#define N_GRAPHS 128

// ---------------------------------------------------------------------------
// K1: degw[i] = 1.0f  (self-loop weight folded into init)
__global__ __launch_bounds__(256) void init_deg_kernel(float* __restrict__ degw) {
    int i = blockIdx.x * 256 + threadIdx.x;
    if (i < N_NODES) degw[i] = 1.0f;
}

// K2: weighted degree (for norm) + integer in-degree count (for CSR)
__global__ __launch_bounds__(256) void count_kernel(const int* __restrict__ dst,
                                                    const float* __restrict__ ew,
                                                    float* __restrict__ degw,
                                                    int* __restrict__ cnt) {
    int e = blockIdx.x * 256 + threadIdx.x;
    if (e < N_EDGES) {
        int d = dst[e];
        atomicAdd(&degw[d], ew[e]);
        atomicAdd(&cnt[d], 1);
    }
}

// K3: degw -> dinv = 1/sqrt(degw)
__global__ __launch_bounds__(256) void rsqrt_kernel(float* __restrict__ degw) {
    int i = blockIdx.x * 256 + threadIdx.x;
    if (i < N_NODES) {
        float d = degw[i];
        degw[i] = (d > 0.0f) ? (1.0f / sqrtf(d)) : 0.0f;
    }
}

// K4: norm[e] = dinv[src]*ew*dinv[dst]
__global__ __launch_bounds__(256) void norm_kernel(const int* __restrict__ src,
                                                   const int* __restrict__ dst,
                                                   const float* __restrict__ ew,
                                                   const float* __restrict__ dinv,
                                                   float* __restrict__ norm) {
    int e = blockIdx.x * 256 + threadIdx.x;
    if (e < N_EDGES) norm[e] = dinv[src[e]] * ew[e] * dinv[dst[e]];
}

// K5: single-block exclusive scan of cnt[50000] -> offsets[50000]
#define SCAN_THREADS 1024
__global__ __launch_bounds__(SCAN_THREADS) void scan_kernel(const int* __restrict__ cnt,
                                                            int* __restrict__ offsets) {
    __shared__ int partial[SCAN_THREADS];
    const int C = (N_NODES + SCAN_THREADS - 1) / SCAN_THREADS;  // 49
    int t = threadIdx.x;
    int base = t * C;
    int s = 0;
    for (int i = 0; i < C; ++i) {
        int idx = base + i;
        if (idx < N_NODES) s += cnt[idx];
    }
    partial[t] = s;
    __syncthreads();
    // Hillis-Steele inclusive scan over 1024 partials
    for (int off = 1; off < SCAN_THREADS; off <<= 1) {
        int v = (t >= off) ? partial[t - off] : 0;
        __syncthreads();
        partial[t] += v;
        __syncthreads();
    }
    int run = (t > 0) ? partial[t - 1] : 0;
    for (int i = 0; i < C; ++i) {
        int idx = base + i;
        if (idx < N_NODES) {
            offsets[idx] = run;
            run += cnt[idx];
        }
    }
}

// K6: bucket edges by dst: src_s/norm_s reordered so each node's incoming
// edges are contiguous. 800k scalar int atomics (position cursors).
__global__ __launch_bounds__(256) void bucket_kernel(const int* __restrict__ src,
                                                     const int* __restrict__ dst,
                                                     const float* __restrict__ norm,
                                                     const int* __restrict__ offsets,
                                                     int* __restrict__ cursor,
                                                     int* __restrict__ src_s,
                                                     float* __restrict__ norm_s) {
    int e = blockIdx.x * 256 + threadIdx.x;
    if (e < N_EDGES) {
        int d = dst[e];
        int pos = offsets[d] + atomicAdd(&cursor[d], 1);
        src_s[pos]  = src[e];
        norm_s[pos] = norm[e];
    }
}

// K7: h = x @ W   [50000x128]@[128x64] f32, W staged in LDS.
__global__ __launch_bounds__(256) void gemm_kernel(const float* __restrict__ x,
                                                   const float* __restrict__ W,
                                                   float* __restrict__ h) {
    __shared__ float Ws[IN_F][HID_F];
    int tid = threadIdx.x;
    for (int i = tid * 4; i < IN_F * HID_F; i += 256 * 4) {
        *(float4*)&((float*)Ws)[i] = *(const float4*)&W[i];
    }
    __syncthreads();

    int row = blockIdx.x * 64 + (tid >> 2);
    int c0  = (tid & 3) * 16;
    if (row >= N_NODES) return;

    float acc[16];
#pragma unroll
    for (int j = 0; j < 16; ++j) acc[j] = 0.0f;

    const float* xr = x + (size_t)row * IN_F;
    for (int k = 0; k < IN_F; k += 4) {
        float4 xv = *(const float4*)&xr[k];
#pragma unroll
        for (int j = 0; j < 16; ++j) {
            acc[j] += xv.x * Ws[k + 0][c0 + j];
            acc[j] += xv.y * Ws[k + 1][c0 + j];
            acc[j] += xv.z * Ws[k + 2][c0 + j];
            acc[j] += xv.w * Ws[k + 3][c0 + j];
        }
    }
    float* hr = h + (size_t)row * HID_F + c0;
#pragma unroll
    for (int j = 0; j < 16; j += 4) {
        *(float4*)&hr[j] = make_float4(acc[j], acc[j + 1], acc[j + 2], acc[j + 3]);
    }
}

// K8: per-node gather-reduce + self-loop + bias + tanh, single plain store.
// One wave per node, lane = feature. 4 nodes / 256-thread block.
__global__ __launch_bounds__(256) void aggregate_kernel(const float* __restrict__ h,
                                                        const int* __restrict__ offsets,
                                                        const int* __restrict__ cnt,
                                                        const int* __restrict__ src_s,
                                                        const float* __restrict__ norm_s,
                                                        const float* __restrict__ dinv,
                                                        const float* __restrict__ b,
                                                        float* __restrict__ nout) {
    int node = blockIdx.x * 4 + (threadIdx.x >> 6);
    if (node >= N_NODES) return;
    int f   = threadIdx.x & 63;
    int beg = offsets[node];
    int end = beg + cnt[node];

    float acc0 = 0.0f, acc1 = 0.0f;
    int j = beg;
    for (; j + 1 < end; j += 2) {
        int   s0 = src_s[j],  s1 = src_s[j + 1];
        float w0 = norm_s[j], w1 = norm_s[j + 1];
        acc0 += h[(size_t)s0 * HID_F + f] * w0;
        acc1 += h[(size_t)s1 * HID_F + f] * w1;
    }
    if (j < end) acc0 += h[(size_t)src_s[j] * HID_F + f] * norm_s[j];

    float di = dinv[node];
    float v  = acc0 + acc1 + h[(size_t)node * HID_F + f] * di * di + b[f];
    nout[(size_t)node * HID_F + f] = tanhf(v);
}

// K9: graph boundaries via binary search over sorted batch.
__global__ void bounds_kernel(const int* __restrict__ batch, int* __restrict__ bounds) {
    int g = threadIdx.x;
    if (g > N_GRAPHS) return;
    int lo = 0, hi = N_NODES;
    while (lo < hi) {
        int m = (lo + hi) >> 1;
        if (batch[m] < g) lo = m + 1; else hi = m;
    }
    bounds[g] = lo;
}

// K10: per-graph mean-pool + [64->32] GEMM + tanh.
__global__ __launch_bounds__(256) void pool_kernel(const float* __restrict__ ne,
                                                   const int* __restrict__ bounds,
                                                   const float* __restrict__ W1,
                                                   const float* __restrict__ b1,
                                                   float* __restrict__ gout) {
    __shared__ float part[4][HID_F];
    __shared__ float mean_s[HID_F];
    int g  = blockIdx.x;
    int f  = threadIdx.x & 63;
    int w  = threadIdx.x >> 6;
    int lo = bounds[g], hi = bounds[g + 1];

    float s = 0.0f;
    for (int i = lo + w; i < hi; i += 4) s += ne[(size_t)i * HID_F + f];
    part[w][f] = s;
    __syncthreads();

    if (w == 0) {
        float m   = part[0][f] + part[1][f] + part[2][f] + part[3][f];
        float cnt = (float)(hi - lo);
        mean_s[f] = m / fmaxf(cnt, 1.0f);
    }
    __syncthreads();

    int o = threadIdx.x;
    if (o < OUT_F) {
        float acc = b1[o];
        for (int k = 0; k < HID_F; ++k) acc += mean_s[k] * W1[k * OUT_F + o];
        gout[(size_t)g * OUT_F + o] = tanhf(acc);
    }
}

extern "C" void kernel_launch(void* const* d_in, const int* in_sizes, int n_in,
                              void* d_out, int out_size, void* d_ws, size_t ws_size,
                              hipStream_t stream) {
    const float* x   = (const float*)d_in[0];
    const int*   ei  = (const int*)d_in[1];          // [2][E]: src row then dst row
    const float* ew  = (const float*)d_in[2];
    const int*   bat = (const int*)d_in[3];
    const float* W   = (const float*)d_in[5];
    const float* b   = (const float*)d_in[6];
    const float* W1  = (const float*)d_in[7];
    const float* b1  = (const float*)d_in[8];

    const int* src = ei;
    const int* dst = ei + N_EDGES;

    float* gout = (float*)d_out;
    float* nout = (float*)d_out + (size_t)N_GRAPHS * OUT_F;

    // Workspace layout (float words):
    // dinv[50000] | h[3.2M] | norm[800k] | norm_s[800k] |
    // cnt[50k]i | cursor[50k]i | offsets[50k]i | src_s[800k]i | bounds[129]i
    float* ws_f    = (float*)d_ws;
    float* dinv    = ws_f;                       // 50,000
    float* h       = ws_f + 50000;               // 3,200,000
    float* norm    = ws_f + 3250000;             // 800,000
    float* norm_s  = ws_f + 4050000;             // 800,000
    int*   cnt     = (int*)(ws_f + 4850000);     // 50,000
    int*   cursor  = (int*)(ws_f + 4900000);     // 50,000
    int*   offsets = (int*)(ws_f + 4950000);     // 50,000
    int*   src_s   = (int*)(ws_f + 5000000);     // 800,000
    int*   bounds  = (int*)(ws_f + 5800000);     // 129

    // zero cnt + cursor (adjacent, 400 KB) — ws is re-poisoned before each call
    hipMemsetAsync(cnt, 0, 2 * (size_t)N_NODES * sizeof(int), stream);

    init_deg_kernel<<<(N_NODES + 255) / 256, 256, 0, stream>>>(dinv);
    count_kernel<<<(N_EDGES + 255) / 256, 256, 0, stream>>>(dst, ew, dinv, cnt);
    rsqrt_kernel<<<(N_NODES + 255) / 256, 256, 0, stream>>>(dinv);
    norm_kernel<<<(N_EDGES + 255) / 256, 256, 0, stream>>>(src, dst, ew, dinv, norm);

    scan_kernel<<<1, SCAN_THREADS, 0, stream>>>(cnt, offsets);
    bucket_kernel<<<(N_EDGES + 255) / 256, 256, 0, stream>>>(src, dst, norm, offsets,
                                                             cursor, src_s, norm_s);

    gemm_kernel<<<(N_NODES + 63) / 64, 256, 0, stream>>>(x, W, h);

    aggregate_kernel<<<(N_NODES + 3) / 4, 256, 0, stream>>>(h, offsets, cnt, src_s,
                                                            norm_s, dinv, b, nout);

    bounds_kernel<<<1, 256, 0, stream>>>(bat, bounds);
    pool_kernel<<<N_GRAPHS, 256, 0, stream>>>(nout, bounds, W1, b1, gout);
}

// Round 5
// 324.151 us; speedup vs baseline: 1.3435x; 1.3435x over previous
//
#include <hip/hip_runtime.h>
#include <math.h>

#define N_NODES  50000
#define N_EDGES  800000
#define IN_F     128
#define HID_F    64
#define OUT_F    32
#define N_GRAPHS 128
#define SCAN_BLOCKS ((N_NODES + 255) / 256)   // 196

// ---------------------------------------------------------------------------
// K1: degw[i] = 1.0f  (self-loop weight folded into init)
__global__ __launch_bounds__(256) void init_deg_kernel(float* __restrict__ degw) {
    int i = blockIdx.x * 256 + threadIdx.x;
    if (i < N_NODES) degw[i] = 1.0f;
}

// K2: weighted degree (for norm) + integer in-degree count (for CSR)
__global__ __launch_bounds__(256) void count_kernel(const int* __restrict__ dst,
                                                    const float* __restrict__ ew,
                                                    float* __restrict__ degw,
                                                    int* __restrict__ cnt) {
    int e = blockIdx.x * 256 + threadIdx.x;
    if (e < N_EDGES) {
        int d = dst[e];
        atomicAdd(&degw[d], ew[e]);
        atomicAdd(&cnt[d], 1);
    }
}

// K3: degw -> dinv = 1/sqrt(degw)
__global__ __launch_bounds__(256) void rsqrt_kernel(float* __restrict__ degw) {
    int i = blockIdx.x * 256 + threadIdx.x;
    if (i < N_NODES) {
        float d = degw[i];
        degw[i] = (d > 0.0f) ? (1.0f / sqrtf(d)) : 0.0f;
    }
}

// ---------------------------------------------------------------------------
// Hierarchical exclusive scan of cnt[50000] -> offsets[50000]
// K4a: per-block (256-wide) sums via wave shuffle reduce
__global__ __launch_bounds__(256) void scan_partial_kernel(const int* __restrict__ cnt,
                                                           int* __restrict__ partials) {
    __shared__ int red[4];
    int i = blockIdx.x * 256 + threadIdx.x;
    int v = (i < N_NODES) ? cnt[i] : 0;
#pragma unroll
    for (int off = 32; off; off >>= 1) v += __shfl_down(v, off, 64);
    int w = threadIdx.x >> 6;
    if ((threadIdx.x & 63) == 0) red[w] = v;
    __syncthreads();
    if (threadIdx.x == 0) partials[blockIdx.x] = red[0] + red[1] + red[2] + red[3];
}

// K4b: single tiny block scans the 196 partials (exclusive)
__global__ __launch_bounds__(256) void scan_top_kernel(const int* __restrict__ partials,
                                                       int* __restrict__ ppref) {
    __shared__ int buf[256];
    int t = threadIdx.x;
    buf[t] = (t < SCAN_BLOCKS) ? partials[t] : 0;
    __syncthreads();
    for (int off = 1; off < 256; off <<= 1) {
        int v = (t >= off) ? buf[t - off] : 0;
        __syncthreads();
        buf[t] += v;
        __syncthreads();
    }
    if (t < SCAN_BLOCKS) ppref[t] = (t > 0) ? buf[t - 1] : 0;
}

// K4c: in-block exclusive scan + add block prefix
__global__ __launch_bounds__(256) void scan_final_kernel(const int* __restrict__ cnt,
                                                         const int* __restrict__ ppref,
                                                         int* __restrict__ offsets) {
    __shared__ int buf[256];
    int t = threadIdx.x;
    int i = blockIdx.x * 256 + t;
    int v = (i < N_NODES) ? cnt[i] : 0;
    buf[t] = v;
    __syncthreads();
    for (int off = 1; off < 256; off <<= 1) {
        int x = (t >= off) ? buf[t - off] : 0;
        __syncthreads();
        buf[t] += x;
        __syncthreads();
    }
    if (i < N_NODES) offsets[i] = ppref[blockIdx.x] + buf[t] - v;
}

// ---------------------------------------------------------------------------
// K5: bucket edges by dst, fused norm computation.
// src_s/norm_s reordered so each node's incoming edges are contiguous.
__global__ __launch_bounds__(256) void bucket_kernel(const int* __restrict__ src,
                                                     const int* __restrict__ dst,
                                                     const float* __restrict__ ew,
                                                     const float* __restrict__ dinv,
                                                     const int* __restrict__ offsets,
                                                     int* __restrict__ cursor,
                                                     int* __restrict__ src_s,
                                                     float* __restrict__ norm_s) {
    int e = blockIdx.x * 256 + threadIdx.x;
    if (e < N_EDGES) {
        int s = src[e], d = dst[e];
        int pos = offsets[d] + atomicAdd(&cursor[d], 1);
        src_s[pos]  = s;
        norm_s[pos] = dinv[s] * ew[e] * dinv[d];
    }
}

// K6: h = x @ W   [50000x128]@[128x64] f32, W staged in LDS.
__global__ __launch_bounds__(256) void gemm_kernel(const float* __restrict__ x,
                                                   const float* __restrict__ W,
                                                   float* __restrict__ h) {
    __shared__ float Ws[IN_F][HID_F];
    int tid = threadIdx.x;
    for (int i = tid * 4; i < IN_F * HID_F; i += 256 * 4) {
        *(float4*)&((float*)Ws)[i] = *(const float4*)&W[i];
    }
    __syncthreads();

    int row = blockIdx.x * 64 + (tid >> 2);
    int c0  = (tid & 3) * 16;
    if (row >= N_NODES) return;

    float acc[16];
#pragma unroll
    for (int j = 0; j < 16; ++j) acc[j] = 0.0f;

    const float* xr = x + (size_t)row * IN_F;
    for (int k = 0; k < IN_F; k += 4) {
        float4 xv = *(const float4*)&xr[k];
#pragma unroll
        for (int j = 0; j < 16; ++j) {
            acc[j] += xv.x * Ws[k + 0][c0 + j];
            acc[j] += xv.y * Ws[k + 1][c0 + j];
            acc[j] += xv.z * Ws[k + 2][c0 + j];
            acc[j] += xv.w * Ws[k + 3][c0 + j];
        }
    }
    float* hr = h + (size_t)row * HID_F + c0;
#pragma unroll
    for (int j = 0; j < 16; j += 4) {
        *(float4*)&hr[j] = make_float4(acc[j], acc[j + 1], acc[j + 2], acc[j + 3]);
    }
}

// K7: per-node gather-reduce + self-loop + bias + tanh, single plain store.
// One wave per node, lane = feature. 4 nodes / 256-thread block.
__global__ __launch_bounds__(256) void aggregate_kernel(const float* __restrict__ h,
                                                        const int* __restrict__ offsets,
                                                        const int* __restrict__ cnt,
                                                        const int* __restrict__ src_s,
                                                        const float* __restrict__ norm_s,
                                                        const float* __restrict__ dinv,
                                                        const float* __restrict__ b,
                                                        float* __restrict__ nout) {
    int node = blockIdx.x * 4 + (threadIdx.x >> 6);
    if (node >= N_NODES) return;
    int f   = threadIdx.x & 63;
    int beg = offsets[node];
    int end = beg + cnt[node];

    float acc0 = 0.0f, acc1 = 0.0f;
    int j = beg;
    for (; j + 1 < end; j += 2) {
        int   s0 = src_s[j],  s1 = src_s[j + 1];
        float w0 = norm_s[j], w1 = norm_s[j + 1];
        acc0 += h[(size_t)s0 * HID_F + f] * w0;
        acc1 += h[(size_t)s1 * HID_F + f] * w1;
    }
    if (j < end) acc0 += h[(size_t)src_s[j] * HID_F + f] * norm_s[j];

    float di = dinv[node];
    float v  = acc0 + acc1 + h[(size_t)node * HID_F + f] * di * di + b[f];
    nout[(size_t)node * HID_F + f] = tanhf(v);
}

// K8: graph boundaries via binary search over sorted batch.
__global__ void bounds_kernel(const int* __restrict__ batch, int* __restrict__ bounds) {
    int g = threadIdx.x;
    if (g > N_GRAPHS) return;
    int lo = 0, hi = N_NODES;
    while (lo < hi) {
        int m = (lo + hi) >> 1;
        if (batch[m] < g) lo = m + 1; else hi = m;
    }
    bounds[g] = lo;
}

// K9: per-graph mean-pool + [64->32] GEMM + tanh.
__global__ __launch_bounds__(256) void pool_kernel(const float* __restrict__ ne,
                                                   const int* __restrict__ bounds,
                                                   const float* __restrict__ W1,
                                                   const float* __restrict__ b1,
                                                   float* __restrict__ gout) {
    __shared__ float part[4][HID_F];
    __shared__ float mean_s[HID_F];
    int g  = blockIdx.x;
    int f  = threadIdx.x & 63;
    int w  = threadIdx.x >> 6;
    int lo = bounds[g], hi = bounds[g + 1];

    float s = 0.0f;
    for (int i = lo + w; i < hi; i += 4) s += ne[(size_t)i * HID_F + f];
    part[w][f] = s;
    __syncthreads();

    if (w == 0) {
        float m   = part[0][f] + part[1][f] + part[2][f] + part[3][f];
        float cnt = (float)(hi - lo);
        mean_s[f] = m / fmaxf(cnt, 1.0f);
    }
    __syncthreads();

    int o = threadIdx.x;
    if (o < OUT_F) {
        float acc = b1[o];
        for (int k = 0; k < HID_F; ++k) acc += mean_s[k] * W1[k * OUT_F + o];
        gout[(size_t)g * OUT_F + o] = tanhf(acc);
    }
}

extern "C" void kernel_launch(void* const* d_in, const int* in_sizes, int n_in,
                              void* d_out, int out_size, void* d_ws, size_t ws_size,
                              hipStream_t stream) {
    const float* x   = (const float*)d_in[0];
    const int*   ei  = (const int*)d_in[1];          // [2][E]: src row then dst row
    const float* ew  = (const float*)d_in[2];
    const int*   bat = (const int*)d_in[3];
    const float* W   = (const float*)d_in[5];
    const float* b   = (const float*)d_in[6];
    const float* W1  = (const float*)d_in[7];
    const float* b1  = (const float*)d_in[8];

    const int* src = ei;
    const int* dst = ei + N_EDGES;

    float* gout = (float*)d_out;
    float* nout = (float*)d_out + (size_t)N_GRAPHS * OUT_F;

    // Workspace layout (float words):
    // dinv[50k] | h[3.2M] | norm_s[800k] | cnt[50k]i | cursor[50k]i |
    // offsets[50k]i | partials[256]i | ppref[256]i | src_s[800k]i | bounds[129]i
    float* ws_f     = (float*)d_ws;
    float* dinv     = ws_f;                        // 50,000
    float* h        = ws_f + 50000;                // 3,200,000
    float* norm_s   = ws_f + 3250000;              // 800,000
    int*   cnt      = (int*)(ws_f + 4050000);      // 50,000
    int*   cursor   = (int*)(ws_f + 4100000);      // 50,000
    int*   offsets  = (int*)(ws_f + 4150000);      // 50,000
    int*   partials = (int*)(ws_f + 4200000);      // 256
    int*   ppref    = (int*)(ws_f + 4200256);      // 256
    int*   src_s    = (int*)(ws_f + 4200512);      // 800,000
    int*   bounds   = (int*)(ws_f + 5000512);      // 129

    // zero cnt + cursor (adjacent, 400 KB) — ws is re-poisoned before each call
    hipMemsetAsync(cnt, 0, 2 * (size_t)N_NODES * sizeof(int), stream);

    init_deg_kernel<<<(N_NODES + 255) / 256, 256, 0, stream>>>(dinv);
    count_kernel<<<(N_EDGES + 255) / 256, 256, 0, stream>>>(dst, ew, dinv, cnt);
    rsqrt_kernel<<<(N_NODES + 255) / 256, 256, 0, stream>>>(dinv);

    scan_partial_kernel<<<SCAN_BLOCKS, 256, 0, stream>>>(cnt, partials);
    scan_top_kernel<<<1, 256, 0, stream>>>(partials, ppref);
    scan_final_kernel<<<SCAN_BLOCKS, 256, 0, stream>>>(cnt, ppref, offsets);

    bucket_kernel<<<(N_EDGES + 255) / 256, 256, 0, stream>>>(src, dst, ew, dinv,
                                                             offsets, cursor,
                                                             src_s, norm_s);

    gemm_kernel<<<(N_NODES + 63) / 64, 256, 0, stream>>>(x, W, h);

    aggregate_kernel<<<(N_NODES + 3) / 4, 256, 0, stream>>>(h, offsets, cnt, src_s,
                                                            norm_s, dinv, b, nout);

    bounds_kernel<<<1, 256, 0, stream>>>(bat, bounds);
    pool_kernel<<<N_GRAPHS, 256, 0, stream>>>(nout, bounds, W1, b1, gout);
}

// Round 6
// 261.235 us; speedup vs baseline: 1.6671x; 1.2408x over previous
//
#include <hip/hip_runtime.h>
#include <math.h>

#define N_NODES  50000
#define N_EDGES  800000
#define IN_F     128
#define HID_F    64
#define OUT_F    32
#define N_GRAPHS 128
#define SCAN_BLOCKS ((N_NODES + 255) / 256)   // 196

// ---------------------------------------------------------------------------
// K1: in-degree histogram + per-edge position. THE only random-atomic pass.
// epos[e] = rank of edge e within its dst bucket.
__global__ __launch_bounds__(256) void histo_kernel(const int* __restrict__ dst,
                                                    int* __restrict__ cnt,
                                                    int* __restrict__ epos) {
    int e = blockIdx.x * 256 + threadIdx.x;
    if (e < N_EDGES) {
        epos[e] = atomicAdd(&cnt[dst[e]], 1);
    }
}

// ---------------------------------------------------------------------------
// Hierarchical exclusive scan of cnt[50000] -> offsets[50000]
// K2a: per-block (256-wide) sums via wave shuffle reduce
__global__ __launch_bounds__(256) void scan_partial_kernel(const int* __restrict__ cnt,
                                                           int* __restrict__ partials) {
    __shared__ int red[4];
    int i = blockIdx.x * 256 + threadIdx.x;
    int v = (i < N_NODES) ? cnt[i] : 0;
#pragma unroll
    for (int off = 32; off; off >>= 1) v += __shfl_down(v, off, 64);
    int w = threadIdx.x >> 6;
    if ((threadIdx.x & 63) == 0) red[w] = v;
    __syncthreads();
    if (threadIdx.x == 0) partials[blockIdx.x] = red[0] + red[1] + red[2] + red[3];
}

// K2b: single tiny block scans the 196 partials (exclusive)
__global__ __launch_bounds__(256) void scan_top_kernel(const int* __restrict__ partials,
                                                       int* __restrict__ ppref) {
    __shared__ int buf[256];
    int t = threadIdx.x;
    buf[t] = (t < SCAN_BLOCKS) ? partials[t] : 0;
    __syncthreads();
    for (int off = 1; off < 256; off <<= 1) {
        int v = (t >= off) ? buf[t - off] : 0;
        __syncthreads();
        buf[t] += v;
        __syncthreads();
    }
    if (t < SCAN_BLOCKS) ppref[t] = (t > 0) ? buf[t - 1] : 0;
}

// K2c: in-block exclusive scan + add block prefix
__global__ __launch_bounds__(256) void scan_final_kernel(const int* __restrict__ cnt,
                                                         const int* __restrict__ ppref,
                                                         int* __restrict__ offsets) {
    __shared__ int buf[256];
    int t = threadIdx.x;
    int i = blockIdx.x * 256 + t;
    int v = (i < N_NODES) ? cnt[i] : 0;
    buf[t] = v;
    __syncthreads();
    for (int off = 1; off < 256; off <<= 1) {
        int x = (t >= off) ? buf[t - off] : 0;
        __syncthreads();
        buf[t] += x;
        __syncthreads();
    }
    if (i < N_NODES) offsets[i] = ppref[blockIdx.x] + buf[t] - v;
}

// ---------------------------------------------------------------------------
// K3: bucket edges by dst — ATOMIC-FREE (positions precomputed in histo).
// Stores {src, ew} as a single 8B int2 per edge.
__global__ __launch_bounds__(256) void bucket_kernel(const int* __restrict__ src,
                                                     const int* __restrict__ dst,
                                                     const float* __restrict__ ew,
                                                     const int* __restrict__ epos,
                                                     const int* __restrict__ offsets,
                                                     int2* __restrict__ edat) {
    int e = blockIdx.x * 256 + threadIdx.x;
    if (e < N_EDGES) {
        int d   = dst[e];
        int pos = offsets[d] + epos[e];
        edat[pos] = make_int2(src[e], __float_as_int(ew[e]));
    }
}

// K4: weighted degree from bucketed CSR (atomic-free) -> dinv = 1/sqrt(1+sum)
__global__ __launch_bounds__(256) void degw_kernel(const int* __restrict__ offsets,
                                                   const int* __restrict__ cnt,
                                                   const int2* __restrict__ edat,
                                                   float* __restrict__ dinv) {
    int n = blockIdx.x * 256 + threadIdx.x;
    if (n >= N_NODES) return;
    int beg = offsets[n], end = beg + cnt[n];
    float s = 1.0f;                               // self-loop weight
    for (int j = beg; j < end; ++j) s += __int_as_float(edat[j].y);
    dinv[n] = 1.0f / sqrtf(s);                    // s >= 1 always
}

// K5: hs = (x @ W) * dinv[row]   [50000x128]@[128x64] f32, W staged in LDS.
// dinv folded into rows so aggregate needs no per-edge dinv[src] gather.
__global__ __launch_bounds__(256) void gemm_kernel(const float* __restrict__ x,
                                                   const float* __restrict__ W,
                                                   const float* __restrict__ dinv,
                                                   float* __restrict__ hs) {
    __shared__ float Ws[IN_F][HID_F];
    int tid = threadIdx.x;
    for (int i = tid * 4; i < IN_F * HID_F; i += 256 * 4) {
        *(float4*)&((float*)Ws)[i] = *(const float4*)&W[i];
    }
    __syncthreads();

    int row = blockIdx.x * 64 + (tid >> 2);
    int c0  = (tid & 3) * 16;
    if (row >= N_NODES) return;

    float acc[16];
#pragma unroll
    for (int j = 0; j < 16; ++j) acc[j] = 0.0f;

    const float* xr = x + (size_t)row * IN_F;
    for (int k = 0; k < IN_F; k += 4) {
        float4 xv = *(const float4*)&xr[k];
#pragma unroll
        for (int j = 0; j < 16; ++j) {
            acc[j] += xv.x * Ws[k + 0][c0 + j];
            acc[j] += xv.y * Ws[k + 1][c0 + j];
            acc[j] += xv.z * Ws[k + 2][c0 + j];
            acc[j] += xv.w * Ws[k + 3][c0 + j];
        }
    }
    float dv = dinv[row];
    float* hr = hs + (size_t)row * HID_F + c0;
#pragma unroll
    for (int j = 0; j < 16; j += 4) {
        *(float4*)&hr[j] = make_float4(acc[j] * dv, acc[j + 1] * dv,
                                       acc[j + 2] * dv, acc[j + 3] * dv);
    }
}

// K6: per-node gather-reduce + self-loop + bias + tanh, single plain store.
// out[n] = tanh(dinv[n]*(sum_j ew_j*hs[src_j] + hs[n]) + b)
// One wave per node, lane = feature. 4 nodes / 256-thread block.
__global__ __launch_bounds__(256) void aggregate_kernel(const float* __restrict__ hs,
                                                        const int* __restrict__ offsets,
                                                        const int* __restrict__ cnt,
                                                        const int2* __restrict__ edat,
                                                        const float* __restrict__ dinv,
                                                        const float* __restrict__ b,
                                                        float* __restrict__ nout) {
    int node = blockIdx.x * 4 + (threadIdx.x >> 6);
    if (node >= N_NODES) return;
    int f   = threadIdx.x & 63;
    int beg = offsets[node];
    int end = beg + cnt[node];

    float acc0 = 0.0f, acc1 = 0.0f;
    int j = beg;
    for (; j + 1 < end; j += 2) {
        int2 e0 = edat[j];
        int2 e1 = edat[j + 1];
        acc0 += hs[(size_t)e0.x * HID_F + f] * __int_as_float(e0.y);
        acc1 += hs[(size_t)e1.x * HID_F + f] * __int_as_float(e1.y);
    }
    if (j < end) {
        int2 e0 = edat[j];
        acc0 += hs[(size_t)e0.x * HID_F + f] * __int_as_float(e0.y);
    }

    float v = dinv[node] * (acc0 + acc1 + hs[(size_t)node * HID_F + f]) + b[f];
    nout[(size_t)node * HID_F + f] = tanhf(v);
}

// K7: graph boundaries via binary search over sorted batch.
__global__ void bounds_kernel(const int* __restrict__ batch, int* __restrict__ bounds) {
    int g = threadIdx.x;
    if (g > N_GRAPHS) return;
    int lo = 0, hi = N_NODES;
    while (lo < hi) {
        int m = (lo + hi) >> 1;
        if (batch[m] < g) lo = m + 1; else hi = m;
    }
    bounds[g] = lo;
}

// K8: per-graph mean-pool + [64->32] GEMM + tanh.
__global__ __launch_bounds__(256) void pool_kernel(const float* __restrict__ ne,
                                                   const int* __restrict__ bounds,
                                                   const float* __restrict__ W1,
                                                   const float* __restrict__ b1,
                                                   float* __restrict__ gout) {
    __shared__ float part[4][HID_F];
    __shared__ float mean_s[HID_F];
    int g  = blockIdx.x;
    int f  = threadIdx.x & 63;
    int w  = threadIdx.x >> 6;
    int lo = bounds[g], hi = bounds[g + 1];

    float s = 0.0f;
    for (int i = lo + w; i < hi; i += 4) s += ne[(size_t)i * HID_F + f];
    part[w][f] = s;
    __syncthreads();

    if (w == 0) {
        float m   = part[0][f] + part[1][f] + part[2][f] + part[3][f];
        float cnt = (float)(hi - lo);
        mean_s[f] = m / fmaxf(cnt, 1.0f);
    }
    __syncthreads();

    int o = threadIdx.x;
    if (o < OUT_F) {
        float acc = b1[o];
        for (int k = 0; k < HID_F; ++k) acc += mean_s[k] * W1[k * OUT_F + o];
        gout[(size_t)g * OUT_F + o] = tanhf(acc);
    }
}

extern "C" void kernel_launch(void* const* d_in, const int* in_sizes, int n_in,
                              void* d_out, int out_size, void* d_ws, size_t ws_size,
                              hipStream_t stream) {
    const float* x   = (const float*)d_in[0];
    const int*   ei  = (const int*)d_in[1];          // [2][E]: src row then dst row
    const float* ew  = (const float*)d_in[2];
    const int*   bat = (const int*)d_in[3];
    const float* W   = (const float*)d_in[5];
    const float* b   = (const float*)d_in[6];
    const float* W1  = (const float*)d_in[7];
    const float* b1  = (const float*)d_in[8];

    const int* src = ei;
    const int* dst = ei + N_EDGES;

    float* gout = (float*)d_out;
    float* nout = (float*)d_out + (size_t)N_GRAPHS * OUT_F;

    // Workspace layout (float words):
    // dinv[50k] | hs[3.2M] | cnt[50k]i | offsets[50k]i | partials[256]i |
    // ppref[256]i | epos[800k]i | edat[800k]int2 | bounds[129]i
    float* ws_f     = (float*)d_ws;
    float* dinv     = ws_f;                        // 50,000
    float* hs       = ws_f + 50000;                // 3,200,000
    int*   cnt      = (int*)(ws_f + 3250000);      // 50,000
    int*   offsets  = (int*)(ws_f + 3300000);      // 50,000
    int*   partials = (int*)(ws_f + 3350000);      // 256
    int*   ppref    = (int*)(ws_f + 3350256);      // 256
    int*   epos     = (int*)(ws_f + 3350512);      // 800,000
    int2*  edat     = (int2*)(ws_f + 4150512);     // 800,000 int2 (8B-aligned)
    int*   bounds   = (int*)(ws_f + 5750512);      // 129

    // zero cnt (200 KB) — ws is re-poisoned before each call
    hipMemsetAsync(cnt, 0, (size_t)N_NODES * sizeof(int), stream);

    histo_kernel<<<(N_EDGES + 255) / 256, 256, 0, stream>>>(dst, cnt, epos);

    scan_partial_kernel<<<SCAN_BLOCKS, 256, 0, stream>>>(cnt, partials);
    scan_top_kernel<<<1, 256, 0, stream>>>(partials, ppref);
    scan_final_kernel<<<SCAN_BLOCKS, 256, 0, stream>>>(cnt, ppref, offsets);

    bucket_kernel<<<(N_EDGES + 255) / 256, 256, 0, stream>>>(src, dst, ew, epos,
                                                             offsets, edat);

    degw_kernel<<<SCAN_BLOCKS, 256, 0, stream>>>(offsets, cnt, edat, dinv);

    gemm_kernel<<<(N_NODES + 63) / 64, 256, 0, stream>>>(x, W, dinv, hs);

    aggregate_kernel<<<(N_NODES + 3) / 4, 256, 0, stream>>>(hs, offsets, cnt, edat,
                                                            dinv, b, nout);

    bounds_kernel<<<1, 256, 0, stream>>>(bat, bounds);
    pool_kernel<<<N_GRAPHS, 256, 0, stream>>>(nout, bounds, W1, b1, gout);
}

// Round 9
// 238.765 us; speedup vs baseline: 1.8240x; 1.0941x over previous
//
#include <hip/hip_runtime.h>
#include <hip/hip_fp16.h>
#include <math.h>

#define N_NODES  50000
#define N_EDGES  800000
#define IN_F     128
#define HID_F    64
#define OUT_F    32
#define N_GRAPHS 128
#define SCAN_BLOCKS  ((N_NODES + 255) / 256)   // 196
#define GEMM_BLOCKS  ((N_NODES + 63) / 64)     // 782 (64 rows/block)
#define HISTO_BLOCKS ((N_EDGES + 255) / 256)   // 3125

// ---------------------------------------------------------------------------
// K1 (fused): grid-partition fusion of GEMM and histogram.
//  blocks [0, GEMM_BLOCKS)            : hs_h = fp16(x @ W)   (no dinv fold)
//  blocks [GEMM_BLOCKS, +HISTO_BLOCKS): epos[e] = atomicAdd(&cnt[dst[e]],1)
// The two phases touch disjoint data and disjoint pipes (VALU/LDS vs TCC
// atomics) — co-resident waves overlap them to ~max instead of sum.
__global__ __launch_bounds__(256) void fused_gemm_histo(const float* __restrict__ x,
                                                        const float* __restrict__ W,
                                                        __half* __restrict__ hs_h,
                                                        const int* __restrict__ dst,
                                                        int* __restrict__ cnt,
                                                        int* __restrict__ epos) {
    __shared__ float Ws[IN_F][HID_F];
    if (blockIdx.x >= GEMM_BLOCKS) {
        int e = (blockIdx.x - GEMM_BLOCKS) * 256 + threadIdx.x;
        if (e < N_EDGES) epos[e] = atomicAdd(&cnt[dst[e]], 1);
        return;
    }

    int tid = threadIdx.x;
    for (int i = tid * 4; i < IN_F * HID_F; i += 256 * 4) {
        *(float4*)&((float*)Ws)[i] = *(const float4*)&W[i];
    }
    __syncthreads();

    int row = blockIdx.x * 64 + (tid >> 2);
    int c0  = (tid & 3) * 16;
    if (row >= N_NODES) return;

    float acc[16];
#pragma unroll
    for (int j = 0; j < 16; ++j) acc[j] = 0.0f;

    const float* xr = x + (size_t)row * IN_F;
    for (int k = 0; k < IN_F; k += 4) {
        float4 xv = *(const float4*)&xr[k];
#pragma unroll
        for (int j = 0; j < 16; ++j) {
            acc[j] += xv.x * Ws[k + 0][c0 + j];
            acc[j] += xv.y * Ws[k + 1][c0 + j];
            acc[j] += xv.z * Ws[k + 2][c0 + j];
            acc[j] += xv.w * Ws[k + 3][c0 + j];
        }
    }
    __half* hr = hs_h + (size_t)row * HID_F + c0;
#pragma unroll
    for (int j = 0; j < 16; j += 2) {
        *(__half2*)&hr[j] = __floats2half2_rn(acc[j], acc[j + 1]);
    }
}

// ---------------------------------------------------------------------------
// Hierarchical exclusive scan of cnt[50000] -> offsets[50000]
__global__ __launch_bounds__(256) void scan_partial_kernel(const int* __restrict__ cnt,
                                                           int* __restrict__ partials) {
    __shared__ int red[4];
    int i = blockIdx.x * 256 + threadIdx.x;
    int v = (i < N_NODES) ? cnt[i] : 0;
#pragma unroll
    for (int off = 32; off; off >>= 1) v += __shfl_down(v, off, 64);
    int w = threadIdx.x >> 6;
    if ((threadIdx.x & 63) == 0) red[w] = v;
    __syncthreads();
    if (threadIdx.x == 0) partials[blockIdx.x] = red[0] + red[1] + red[2] + red[3];
}

__global__ __launch_bounds__(256) void scan_top_kernel(const int* __restrict__ partials,
                                                       int* __restrict__ ppref) {
    __shared__ int buf[256];
    int t = threadIdx.x;
    buf[t] = (t < SCAN_BLOCKS) ? partials[t] : 0;
    __syncthreads();
    for (int off = 1; off < 256; off <<= 1) {
        int v = (t >= off) ? buf[t - off] : 0;
        __syncthreads();
        buf[t] += v;
        __syncthreads();
    }
    if (t < SCAN_BLOCKS) ppref[t] = (t > 0) ? buf[t - 1] : 0;
}

__global__ __launch_bounds__(256) void scan_final_kernel(const int* __restrict__ cnt,
                                                         const int* __restrict__ ppref,
                                                         int* __restrict__ offsets) {
    __shared__ int buf[256];
    int t = threadIdx.x;
    int i = blockIdx.x * 256 + t;
    int v = (i < N_NODES) ? cnt[i] : 0;
    buf[t] = v;
    __syncthreads();
    for (int off = 1; off < 256; off <<= 1) {
        int x = (t >= off) ? buf[t - off] : 0;
        __syncthreads();
        buf[t] += x;
        __syncthreads();
    }
    if (i < N_NODES) offsets[i] = ppref[blockIdx.x] + buf[t] - v;
}

// ---------------------------------------------------------------------------
// K3: bucket edges by dst — atomic-free (positions precomputed in histo).
__global__ __launch_bounds__(256) void bucket_kernel(const int* __restrict__ src,
                                                     const int* __restrict__ dst,
                                                     const float* __restrict__ ew,
                                                     const int* __restrict__ epos,
                                                     const int* __restrict__ offsets,
                                                     int2* __restrict__ edat) {
    int e = blockIdx.x * 256 + threadIdx.x;
    if (e < N_EDGES) {
        int d   = dst[e];
        int pos = offsets[d] + epos[e];
        edat[pos] = make_int2(src[e], __float_as_int(ew[e]));
    }
}

// K4: weighted degree from bucketed CSR -> dinv = 1/sqrt(1+sum)
__global__ __launch_bounds__(256) void degw_kernel(const int* __restrict__ offsets,
                                                   const int* __restrict__ cnt,
                                                   const int2* __restrict__ edat,
                                                   float* __restrict__ dinv) {
    int n = blockIdx.x * 256 + threadIdx.x;
    if (n >= N_NODES) return;
    int beg = offsets[n], end = beg + cnt[n];
    float s = 1.0f;                               // self-loop weight
    for (int j = beg; j < end; ++j) s += __int_as_float(edat[j].y);
    dinv[n] = 1.0f / sqrtf(s);
}

// K5: per-node gather-reduce + self-loop + bias + tanh.
// out[n] = tanh(dinv[n]*(sum_j ew_j*dinv[s_j]*h[s_j] + dinv[n]*h[n]) + b)
// One wave per node, lane = feature (fp16 h gather = 128 B/edge/wave).
__global__ __launch_bounds__(256) void aggregate_kernel(const __half* __restrict__ hs_h,
                                                        const int* __restrict__ offsets,
                                                        const int* __restrict__ cnt,
                                                        const int2* __restrict__ edat,
                                                        const float* __restrict__ dinv,
                                                        const float* __restrict__ b,
                                                        float* __restrict__ nout) {
    int node = blockIdx.x * 4 + (threadIdx.x >> 6);
    if (node >= N_NODES) return;
    int f   = threadIdx.x & 63;
    int beg = offsets[node];
    int end = beg + cnt[node];

    float acc0 = 0.0f, acc1 = 0.0f;
    int j = beg;
    for (; j + 1 < end; j += 2) {
        int2 e0 = edat[j];
        int2 e1 = edat[j + 1];
        float w0 = dinv[e0.x] * __int_as_float(e0.y);
        float w1 = dinv[e1.x] * __int_as_float(e1.y);
        acc0 += __half2float(hs_h[(size_t)e0.x * HID_F + f]) * w0;
        acc1 += __half2float(hs_h[(size_t)e1.x * HID_F + f]) * w1;
    }
    if (j < end) {
        int2 e0 = edat[j];
        acc0 += __half2float(hs_h[(size_t)e0.x * HID_F + f]) *
                (dinv[e0.x] * __int_as_float(e0.y));
    }

    float dn = dinv[node];
    float self = __half2float(hs_h[(size_t)node * HID_F + f]) * dn;
    float v = dn * (acc0 + acc1 + self) + b[f];
    nout[(size_t)node * HID_F + f] = tanhf(v);
}

// K6: graph boundaries via binary search over sorted batch.
__global__ void bounds_kernel(const int* __restrict__ batch, int* __restrict__ bounds) {
    int g = threadIdx.x;
    if (g > N_GRAPHS) return;
    int lo = 0, hi = N_NODES;
    while (lo < hi) {
        int m = (lo + hi) >> 1;
        if (batch[m] < g) lo = m + 1; else hi = m;
    }
    bounds[g] = lo;
}

// K7: per-graph mean-pool + [64->32] GEMM + tanh.
__global__ __launch_bounds__(256) void pool_kernel(const float* __restrict__ ne,
                                                   const int* __restrict__ bounds,
                                                   const float* __restrict__ W1,
                                                   const float* __restrict__ b1,
                                                   float* __restrict__ gout) {
    __shared__ float part[4][HID_F];
    __shared__ float mean_s[HID_F];
    int g  = blockIdx.x;
    int f  = threadIdx.x & 63;
    int w  = threadIdx.x >> 6;
    int lo = bounds[g], hi = bounds[g + 1];

    float s = 0.0f;
    for (int i = lo + w; i < hi; i += 4) s += ne[(size_t)i * HID_F + f];
    part[w][f] = s;
    __syncthreads();

    if (w == 0) {
        float m   = part[0][f] + part[1][f] + part[2][f] + part[3][f];
        float cnt = (float)(hi - lo);
        mean_s[f] = m / fmaxf(cnt, 1.0f);
    }
    __syncthreads();

    int o = threadIdx.x;
    if (o < OUT_F) {
        float acc = b1[o];
        for (int k = 0; k < HID_F; ++k) acc += mean_s[k] * W1[k * OUT_F + o];
        gout[(size_t)g * OUT_F + o] = tanhf(acc);
    }
}

extern "C" void kernel_launch(void* const* d_in, const int* in_sizes, int n_in,
                              void* d_out, int out_size, void* d_ws, size_t ws_size,
                              hipStream_t stream) {
    const float* x   = (const float*)d_in[0];
    const int*   ei  = (const int*)d_in[1];          // [2][E]: src row then dst row
    const float* ew  = (const float*)d_in[2];
    const int*   bat = (const int*)d_in[3];
    const float* W   = (const float*)d_in[5];
    const float* b   = (const float*)d_in[6];
    const float* W1  = (const float*)d_in[7];
    const float* b1  = (const float*)d_in[8];

    const int* src = ei;
    const int* dst = ei + N_EDGES;

    float* gout = (float*)d_out;
    float* nout = (float*)d_out + (size_t)N_GRAPHS * OUT_F;

    // Workspace layout (float words):
    // dinv[50k] | hs_h[1.6M words = 3.2M halves] | cnt[50k]i | offsets[50k]i |
    // partials[256]i | ppref[256]i | epos[800k]i | edat[800k]int2 | bounds[129]i
    float*  ws_f     = (float*)d_ws;
    float*  dinv     = ws_f;                        // 50,000
    __half* hs_h     = (__half*)(ws_f + 50000);     // 3,200,000 halves
    int*    cnt      = (int*)(ws_f + 1650000);      // 50,000
    int*    offsets  = (int*)(ws_f + 1700000);      // 50,000
    int*    partials = (int*)(ws_f + 1750000);      // 256
    int*    ppref    = (int*)(ws_f + 1750256);      // 256
    int*    epos     = (int*)(ws_f + 1750512);      // 800,000
    int2*   edat     = (int2*)(ws_f + 2550512);     // 800,000 int2 (8B-aligned)
    int*    bounds   = (int*)(ws_f + 4150512);      // 129

    // zero cnt (200 KB) — ws is re-poisoned before each call
    hipMemsetAsync(cnt, 0, (size_t)N_NODES * sizeof(int), stream);

    fused_gemm_histo<<<GEMM_BLOCKS + HISTO_BLOCKS, 256, 0, stream>>>(
        x, W, hs_h, dst, cnt, epos);

    scan_partial_kernel<<<SCAN_BLOCKS, 256, 0, stream>>>(cnt, partials);
    scan_top_kernel<<<1, 256, 0, stream>>>(partials, ppref);
    scan_final_kernel<<<SCAN_BLOCKS, 256, 0, stream>>>(cnt, ppref, offsets);

    bucket_kernel<<<HISTO_BLOCKS, 256, 0, stream>>>(src, dst, ew, epos,
                                                    offsets, edat);

    degw_kernel<<<SCAN_BLOCKS, 256, 0, stream>>>(offsets, cnt, edat, dinv);

    aggregate_kernel<<<(N_NODES + 3) / 4, 256, 0, stream>>>(hs_h, offsets, cnt, edat,
                                                            dinv, b, nout);

    bounds_kernel<<<1, 256, 0, stream>>>(bat, bounds);
    pool_kernel<<<N_GRAPHS, 256, 0, stream>>>(nout, bounds, W1, b1, gout);
}

// Round 12
// 232.012 us; speedup vs baseline: 1.8771x; 1.0291x over previous
//
#include <hip/hip_runtime.h>
#include <hip/hip_fp16.h>
#include <math.h>

#define N_NODES  50000
#define N_EDGES  800000
#define IN_F     128
#define HID_F    64
#define OUT_F    32
#define N_GRAPHS 128
#define SCAN_BLOCKS  ((N_NODES + 255) / 256)   // 196
#define GEMM_BLOCKS  ((N_NODES + 127) / 128)   // 391 (128 rows/block, 2 rows/thread)
#define HISTO_BLOCKS ((N_EDGES + 255) / 256)   // 3125

// ---------------------------------------------------------------------------
// K1 (fused): grid-partition fusion of GEMM and histogram.
//  blocks [0, GEMM_BLOCKS)            : hs_h = fp16(x @ W)
//  blocks [GEMM_BLOCKS, +HISTO_BLOCKS): epos[e] = atomicAdd(&cnt[dst[e]],1)
// GEMM is 2-rows-per-thread register-blocked: each LDS Ws read feeds 2 FMAs,
// halving LDS traffic (the previous GEMM bottleneck).
__global__ __launch_bounds__(256) void fused_gemm_histo(const float* __restrict__ x,
                                                        const float* __restrict__ W,
                                                        __half* __restrict__ hs_h,
                                                        const int* __restrict__ dst,
                                                        int* __restrict__ cnt,
                                                        int* __restrict__ epos) {
    __shared__ float Ws[IN_F][HID_F];
    if (blockIdx.x >= GEMM_BLOCKS) {
        int e = (blockIdx.x - GEMM_BLOCKS) * 256 + threadIdx.x;
        if (e < N_EDGES) epos[e] = atomicAdd(&cnt[dst[e]], 1);
        return;
    }

    int tid = threadIdx.x;
    for (int i = tid * 4; i < IN_F * HID_F; i += 256 * 4) {
        *(float4*)&((float*)Ws)[i] = *(const float4*)&W[i];
    }
    __syncthreads();

    int r0 = blockIdx.x * 128 + (tid >> 2);   // rows r0 and r0+64
    int r1 = r0 + 64;
    int c0 = (tid & 3) * 16;
    if (r0 >= N_NODES) return;
    bool has1 = (r1 < N_NODES);

    float acc0[16], acc1[16];
#pragma unroll
    for (int j = 0; j < 16; ++j) { acc0[j] = 0.0f; acc1[j] = 0.0f; }

    const float* xr0 = x + (size_t)r0 * IN_F;
    const float* xr1 = x + (size_t)r1 * IN_F;
    for (int k = 0; k < IN_F; k += 4) {
        float4 xa = *(const float4*)&xr0[k];
        float4 xb = has1 ? *(const float4*)&xr1[k] : make_float4(0, 0, 0, 0);
#pragma unroll
        for (int j = 0; j < 16; ++j) {
            float w0 = Ws[k + 0][c0 + j];
            float w1 = Ws[k + 1][c0 + j];
            float w2 = Ws[k + 2][c0 + j];
            float w3 = Ws[k + 3][c0 + j];
            acc0[j] += xa.x * w0 + xa.y * w1 + xa.z * w2 + xa.w * w3;
            acc1[j] += xb.x * w0 + xb.y * w1 + xb.z * w2 + xb.w * w3;
        }
    }
    __half* hr0 = hs_h + (size_t)r0 * HID_F + c0;
#pragma unroll
    for (int j = 0; j < 16; j += 2) {
        *(__half2*)&hr0[j] = __floats2half2_rn(acc0[j], acc0[j + 1]);
    }
    if (has1) {
        __half* hr1 = hs_h + (size_t)r1 * HID_F + c0;
#pragma unroll
        for (int j = 0; j < 16; j += 2) {
            *(__half2*)&hr1[j] = __floats2half2_rn(acc1[j], acc1[j + 1]);
        }
    }
}

// ---------------------------------------------------------------------------
// Hierarchical exclusive scan of cnt[50000] -> offsets[50000]
__global__ __launch_bounds__(256) void scan_partial_kernel(const int* __restrict__ cnt,
                                                           int* __restrict__ partials) {
    __shared__ int red[4];
    int i = blockIdx.x * 256 + threadIdx.x;
    int v = (i < N_NODES) ? cnt[i] : 0;
#pragma unroll
    for (int off = 32; off; off >>= 1) v += __shfl_down(v, off, 64);
    int w = threadIdx.x >> 6;
    if ((threadIdx.x & 63) == 0) red[w] = v;
    __syncthreads();
    if (threadIdx.x == 0) partials[blockIdx.x] = red[0] + red[1] + red[2] + red[3];
}

__global__ __launch_bounds__(256) void scan_top_kernel(const int* __restrict__ partials,
                                                       int* __restrict__ ppref) {
    __shared__ int buf[256];
    int t = threadIdx.x;
    buf[t] = (t < SCAN_BLOCKS) ? partials[t] : 0;
    __syncthreads();
    for (int off = 1; off < 256; off <<= 1) {
        int v = (t >= off) ? buf[t - off] : 0;
        __syncthreads();
        buf[t] += v;
        __syncthreads();
    }
    if (t < SCAN_BLOCKS) ppref[t] = (t > 0) ? buf[t - 1] : 0;
}

__global__ __launch_bounds__(256) void scan_final_kernel(const int* __restrict__ cnt,
                                                         const int* __restrict__ ppref,
                                                         int* __restrict__ offsets) {
    __shared__ int buf[256];
    int t = threadIdx.x;
    int i = blockIdx.x * 256 + t;
    int v = (i < N_NODES) ? cnt[i] : 0;
    buf[t] = v;
    __syncthreads();
    for (int off = 1; off < 256; off <<= 1) {
        int x = (t >= off) ? buf[t - off] : 0;
        __syncthreads();
        buf[t] += x;
        __syncthreads();
    }
    if (i < N_NODES) offsets[i] = ppref[blockIdx.x] + buf[t] - v;
}

// ---------------------------------------------------------------------------
// K3: bucket edges by dst — atomic-free (positions precomputed in histo).
__global__ __launch_bounds__(256) void bucket_kernel(const int* __restrict__ src,
                                                     const int* __restrict__ dst,
                                                     const float* __restrict__ ew,
                                                     const int* __restrict__ epos,
                                                     const int* __restrict__ offsets,
                                                     int2* __restrict__ edat) {
    int e = blockIdx.x * 256 + threadIdx.x;
    if (e < N_EDGES) {
        int d   = dst[e];
        int pos = offsets[d] + epos[e];
        edat[pos] = make_int2(src[e], __float_as_int(ew[e]));
    }
}

// K4: weighted degree from bucketed CSR -> dinv = 1/sqrt(1+sum)
__global__ __launch_bounds__(256) void degw_kernel(const int* __restrict__ offsets,
                                                   const int* __restrict__ cnt,
                                                   const int2* __restrict__ edat,
                                                   float* __restrict__ dinv) {
    int n = blockIdx.x * 256 + threadIdx.x;
    if (n >= N_NODES) return;
    int beg = offsets[n], end = beg + cnt[n];
    float s = 1.0f;                               // self-loop weight
    for (int j = beg; j < end; ++j) s += __int_as_float(edat[j].y);
    dinv[n] = 1.0f / sqrtf(s);
}

// K5: per-node gather-reduce + self-loop + bias + tanh.
// One wave per node. Lane layout: lane = half*32 + fl; lane holds feature
// pair {2fl, 2fl+1} as __half2 (one dword). lo half processes even-offset
// edges, hi half odd-offset; 2-way unroll -> 4 outstanding gathers/wave
// (2x the previous layout — attacks the measured latency-bound regime).
__global__ __launch_bounds__(256) void aggregate_kernel(const __half* __restrict__ hs_h,
                                                        const int* __restrict__ offsets,
                                                        const int* __restrict__ cnt,
                                                        const int2* __restrict__ edat,
                                                        const float* __restrict__ dinv,
                                                        const float* __restrict__ b,
                                                        float* __restrict__ nout) {
    int node = blockIdx.x * 4 + (threadIdx.x >> 6);
    if (node >= N_NODES) return;
    int lane = threadIdx.x & 63;
    int half = lane >> 5;        // 0: even-offset edges, 1: odd-offset
    int fl   = lane & 31;        // feature pair index
    int beg  = offsets[node];
    int end  = beg + cnt[node];

    float ax0 = 0.0f, ay0 = 0.0f, ax1 = 0.0f, ay1 = 0.0f;
    int j = beg + half;
    for (; j + 2 < end; j += 4) {                 // edges j and j+2 (this half)
        int2 e0 = edat[j];
        int2 e1 = edat[j + 2];
        float w0 = dinv[e0.x] * __int_as_float(e0.y);
        float w1 = dinv[e1.x] * __int_as_float(e1.y);
        float2 h0 = __half22float2(*(const __half2*)&hs_h[(size_t)e0.x * HID_F + 2 * fl]);
        float2 h1 = __half22float2(*(const __half2*)&hs_h[(size_t)e1.x * HID_F + 2 * fl]);
        ax0 += h0.x * w0; ay0 += h0.y * w0;
        ax1 += h1.x * w1; ay1 += h1.y * w1;
    }
    if (j < end) {                                // at most one edge left/half
        int2 e0 = edat[j];
        float w0 = dinv[e0.x] * __int_as_float(e0.y);
        float2 h0 = __half22float2(*(const __half2*)&hs_h[(size_t)e0.x * HID_F + 2 * fl]);
        ax0 += h0.x * w0; ay0 += h0.y * w0;
    }

    float sx = ax0 + ax1;
    float sy = ay0 + ay1;
    // merge the two halves: lane L gets lane L^32's partial
    sx += __shfl_xor(sx, 32, 64);
    sy += __shfl_xor(sy, 32, 64);

    if (half == 0) {
        float dn = dinv[node];
        float2 hself = __half22float2(*(const __half2*)&hs_h[(size_t)node * HID_F + 2 * fl]);
        float2 bb = *(const float2*)&b[2 * fl];
        float vx = dn * (sx + hself.x * dn) + bb.x;
        float vy = dn * (sy + hself.y * dn) + bb.y;
        *(float2*)&nout[(size_t)node * HID_F + 2 * fl] = make_float2(tanhf(vx), tanhf(vy));
    }
}

// K6: graph boundaries via binary search over sorted batch.
__global__ void bounds_kernel(const int* __restrict__ batch, int* __restrict__ bounds) {
    int g = threadIdx.x;
    if (g > N_GRAPHS) return;
    int lo = 0, hi = N_NODES;
    while (lo < hi) {
        int m = (lo + hi) >> 1;
        if (batch[m] < g) lo = m + 1; else hi = m;
    }
    bounds[g] = lo;
}

// K7: per-graph mean-pool + [64->32] GEMM + tanh.
__global__ __launch_bounds__(256) void pool_kernel(const float* __restrict__ ne,
                                                   const int* __restrict__ bounds,
                                                   const float* __restrict__ W1,
                                                   const float* __restrict__ b1,
                                                   float* __restrict__ gout) {
    __shared__ float part[4][HID_F];
    __shared__ float mean_s[HID_F];
    int g  = blockIdx.x;
    int f  = threadIdx.x & 63;
    int w  = threadIdx.x >> 6;
    int lo = bounds[g], hi = bounds[g + 1];

    float s = 0.0f;
    for (int i = lo + w; i < hi; i += 4) s += ne[(size_t)i * HID_F + f];
    part[w][f] = s;
    __syncthreads();

    if (w == 0) {
        float m   = part[0][f] + part[1][f] + part[2][f] + part[3][f];
        float cnt = (float)(hi - lo);
        mean_s[f] = m / fmaxf(cnt, 1.0f);
    }
    __syncthreads();

    int o = threadIdx.x;
    if (o < OUT_F) {
        float acc = b1[o];
        for (int k = 0; k < HID_F; ++k) acc += mean_s[k] * W1[k * OUT_F + o];
        gout[(size_t)g * OUT_F + o] = tanhf(acc);
    }
}

extern "C" void kernel_launch(void* const* d_in, const int* in_sizes, int n_in,
                              void* d_out, int out_size, void* d_ws, size_t ws_size,
                              hipStream_t stream) {
    const float* x   = (const float*)d_in[0];
    const int*   ei  = (const int*)d_in[1];          // [2][E]: src row then dst row
    const float* ew  = (const float*)d_in[2];
    const int*   bat = (const int*)d_in[3];
    const float* W   = (const float*)d_in[5];
    const float* b   = (const float*)d_in[6];
    const float* W1  = (const float*)d_in[7];
    const float* b1  = (const float*)d_in[8];

    const int* src = ei;
    const int* dst = ei + N_EDGES;

    float* gout = (float*)d_out;
    float* nout = (float*)d_out + (size_t)N_GRAPHS * OUT_F;

    // Workspace layout (float words):
    // dinv[50k] | hs_h[1.6M words = 3.2M halves] | cnt[50k]i | offsets[50k]i |
    // partials[256]i | ppref[256]i | epos[800k]i | edat[800k]int2 | bounds[129]i
    float*  ws_f     = (float*)d_ws;
    float*  dinv     = ws_f;                        // 50,000
    __half* hs_h     = (__half*)(ws_f + 50000);     // 3,200,000 halves
    int*    cnt      = (int*)(ws_f + 1650000);      // 50,000
    int*    offsets  = (int*)(ws_f + 1700000);      // 50,000
    int*    partials = (int*)(ws_f + 1750000);      // 256
    int*    ppref    = (int*)(ws_f + 1750256);      // 256
    int*    epos     = (int*)(ws_f + 1750512);      // 800,000
    int2*   edat     = (int2*)(ws_f + 2550512);     // 800,000 int2 (8B-aligned)
    int*    bounds   = (int*)(ws_f + 4150512);      // 129

    // zero cnt (200 KB) — ws is re-poisoned before each call
    hipMemsetAsync(cnt, 0, (size_t)N_NODES * sizeof(int), stream);

    fused_gemm_histo<<<GEMM_BLOCKS + HISTO_BLOCKS, 256, 0, stream>>>(
        x, W, hs_h, dst, cnt, epos);

    scan_partial_kernel<<<SCAN_BLOCKS, 256, 0, stream>>>(cnt, partials);
    scan_top_kernel<<<1, 256, 0, stream>>>(partials, ppref);
    scan_final_kernel<<<SCAN_BLOCKS, 256, 0, stream>>>(cnt, ppref, offsets);

    bucket_kernel<<<HISTO_BLOCKS, 256, 0, stream>>>(src, dst, ew, epos,
                                                    offsets, edat);

    degw_kernel<<<SCAN_BLOCKS, 256, 0, stream>>>(offsets, cnt, edat, dinv);

    aggregate_kernel<<<(N_NODES + 3) / 4, 256, 0, stream>>>(hs_h, offsets, cnt, edat,
                                                            dinv, b, nout);

    bounds_kernel<<<1, 256, 0, stream>>>(bat, bounds);
    pool_kernel<<<N_GRAPHS, 256, 0, stream>>>(nout, bounds, W1, b1, gout);
}